// Round 1
// baseline (317.481 us; speedup 1.0000x reference)
//
#include <hip/hip_runtime.h>
#include <hip/hip_bf16.h>

#define IMG_H 512
#define IMG_W 512
#define PAD   256      // max_size = GS * 2^(N_GLIMPSES-1)
#define HP    1024     // padded height/width
#define BATCH 64
#define KTOT  36864    // 64*64*9 contraction length
#define KTILE 96       // K per GEMM block (3 MFMA k-steps of 32)
#define NTILES 384     // KTOT / KTILE
#define TBLK  1152     // transpose blocks in prep kernel (576 k-tiles x 2 n-tiles)

typedef __attribute__((ext_vector_type(8))) short short8;
typedef __attribute__((ext_vector_type(4))) float f32x4;

// Keys cubic kernel, a = -0.5 (matches jax.image resize 'cubic')
__device__ __forceinline__ float keys_cubic(float x) {
  if (x >= 2.0f) return 0.0f;
  if (x >= 1.0f) return ((-0.5f * x + 2.5f) * x - 4.0f) * x + 2.0f;
  return ((1.5f * x - 2.5f) * x) * x + 1.0f;
}

__device__ __forceinline__ int iclamp(int v, int lo, int hi) {
  return min(max(v, lo), hi);
}
__device__ __forceinline__ unsigned short f2bits(float f) {
  __hip_bfloat16 h = __float2bfloat16(f);
  unsigned short s;
  __builtin_memcpy(&s, &h, 2);
  return s;
}

// ---------------------------------------------------------------------------
// prep_kernel: blocks 0..1151 transpose+convert Wg[36864][128] f32 ->
// Wt[128][36864] bf16 (K-major so GEMM B-fragments are single dwordx4 loads).
// Block 1152 generates the cubic weight tables (shared by vertical AND
// horizontal passes of the resize — identical formulas):
//   WT[xo*9  + t] raw w, WT[xo*9+8]  = wsum   (scale1, 8 taps, range 128)
//   WT[576+xo*17+t] raw, WT[...+16]  = wsum   (scale2, 16 taps, range 256)
// Expressions are bit-identical to the previous in-kernel computation.
// ---------------------------------------------------------------------------
__global__ __launch_bounds__(256) void prep_kernel(
    const float* __restrict__ Wg, unsigned short* __restrict__ Wt,
    float* __restrict__ WT) {
  if (blockIdx.x == TBLK) {  // weight-table generation
    const int t = threadIdx.x;
    if (t < 64) {
      float sx = ((float)t + 0.5f) * 2.0f - 0.5f;
      int ix0 = (int)ceilf(sx - 4.0f);
      float ws = 0.0f;
#pragma unroll
      for (int tap = 0; tap < 8; ++tap) {
        int i = ix0 + tap;
        float w = (i >= 0 && i < 128) ? keys_cubic(fabsf(sx - (float)i) * 0.5f) : 0.0f;
        WT[t * 9 + tap] = w;
        ws += w;
      }
      WT[t * 9 + 8] = ws;
    } else if (t < 128) {
      const int xo = t - 64;
      float sx = ((float)xo + 0.5f) * 4.0f - 0.5f;
      int ix0 = (int)ceilf(sx - 8.0f);
      float ws = 0.0f;
#pragma unroll
      for (int tap = 0; tap < 16; ++tap) {
        int i = ix0 + tap;
        float w = (i >= 0 && i < 256) ? keys_cubic(fabsf(sx - (float)i) * 0.25f) : 0.0f;
        WT[576 + xo * 17 + tap] = w;
        ws += w;
      }
      WT[576 + xo * 17 + 16] = ws;
    }
    return;
  }

  // 64(k) x 64(n) tile transpose via LDS
  __shared__ float T[64][68];  // +4 pad: conflict-light, rows 16B-aligned (272B)
  const int tid = threadIdx.x;
  const int kt  = (blockIdx.x % 576) * 64;
  const int nt0 = (blockIdx.x / 576) * 64;
  {
    const int r = tid >> 4, nc = tid & 15;
#pragma unroll
    for (int kk = 0; kk < 4; ++kk) {
      const int k = kk * 16 + r;
      const float4 v = *(const float4*)(Wg + (size_t)(kt + k) * 128 + nt0 + nc * 4);
      *(float4*)(&T[k][nc * 4]) = v;
    }
  }
  __syncthreads();
#pragma unroll
  for (int it = 0; it < 2; ++it) {
    const int item = tid + 256 * it;
    const int n = item & 63, ko = item >> 6;  // lanes: consecutive n -> conflict-free LDS reads
    short8 o;
#pragma unroll
    for (int j = 0; j < 8; ++j) o[j] = (short)f2bits(T[ko * 8 + j][n]);
    *(short8*)(Wt + (size_t)(nt0 + n) * KTOT + kt + ko * 8) = o;
  }
}

// ---------------------------------------------------------------------------
// One block per (b, y): all 3 scales of output row y for batch b.
// Weight tables are loaded from global (L2-hot) instead of recomputed
// per-thread; arithmetic on pixel data is bit-identical to previous kernel.
// ---------------------------------------------------------------------------
__global__ __launch_bounds__(256) void glimpse_kernel(
    const float* __restrict__ img, const float* __restrict__ loc,
    const float* __restrict__ WT, unsigned short* __restrict__ G) {
  __shared__ __align__(16) float Ws[1664];  // [64][9] scale1 | [64][17] scale2
  __shared__ float wv1n[8], wv2n[16];       // normalized vertical weights, this y
  __shared__ float tmp1[384];               // sc=1 vertical result: 128 cols x 3 ch
  __shared__ float tmp2[768];               // sc=2 vertical result: 256 cols x 3 ch
  const int y   = blockIdx.x & 63;
  const int b   = blockIdx.x >> 6;
  const int tid = threadIdx.x;

  {  // stage weight tables: 1664 floats = 416 float4
    const float4* src = (const float4*)WT;
    float4* dst = (float4*)Ws;
    for (int e = tid; e < 416; e += 256) dst[e] = src[e];
  }

  // center / top-left: bit-identical to reference fp32 math, banker's rounding
  const float cy = (loc[2 * b] + 1.0f) * 0.5f * 1024.0f;
  const float cx = (loc[2 * b + 1] + 1.0f) * 0.5f * 1024.0f;
  const int tly0 = iclamp((int)rintf(cy - 32.0f), 0, HP - 64);
  const int tlx0 = iclamp((int)rintf(cx - 32.0f), 0, HP - 64);
  const int tly1 = iclamp((int)rintf(cy - 64.0f), 0, HP - 128);
  const int tlx1 = iclamp((int)rintf(cx - 64.0f), 0, HP - 128);
  const int tly2 = iclamp((int)rintf(cy - 128.0f), 0, HP - 256);
  const int tlx2 = iclamp((int)rintf(cx - 128.0f), 0, HP - 256);
  const float* imb = img + (size_t)b * (IMG_H * IMG_W * 3);
  unsigned short* Grow = G + ((size_t)b * 64 + y) * (64 * 9);

  // ---- scale 0: 64->64 resize is exactly identity: zero-padded crop copy ----
  if (tid < 192) {
    int x = tid / 3, c = tid - 3 * (tid / 3);
    int py = tly0 + y - PAD, px = tlx0 + x - PAD;
    float v = 0.0f;
    if ((unsigned)py < (unsigned)IMG_H && (unsigned)px < (unsigned)IMG_W)
      v = imb[(py * IMG_W + px) * 3 + c];
    Grow[x * 9 + c] = f2bits(v);
  }
  __syncthreads();  // tables staged

  // normalize vertical weights once per block (same exprs as before: w * (1/ws))
  if (tid < 8) {
    wv1n[tid] = Ws[y * 9 + tid] * (1.0f / Ws[y * 9 + 8]);
  } else if (tid >= 64 && tid < 80) {
    const int t = tid - 64;
    wv2n[t] = Ws[576 + y * 17 + t] * (1.0f / Ws[576 + y * 17 + 16]);
  }
  __syncthreads();

  const float sy1 = ((float)y + 0.5f) * 2.0f - 0.5f;
  const int iy0_1 = (int)ceilf(sy1 - 4.0f);
  const float sy2 = ((float)y + 0.5f) * 4.0f - 0.5f;
  const int iy0_2 = (int)ceilf(sy2 - 8.0f);
  float rw1[8], rw2[16];
#pragma unroll
  for (int t = 0; t < 8; ++t) rw1[t] = wv1n[t];
#pragma unroll
  for (int t = 0; t < 16; ++t) rw2[t] = wv2n[t];

  // ---- vertical pass, scale 1: 384 elements ----
  for (int e = tid; e < 384; e += 256) {
    int x = e / 3, c = e - 3 * (e / 3);
    int px = tlx1 - PAD + x;
    float a = 0.0f;
    if ((unsigned)px < (unsigned)IMG_W) {
      const float* colp = imb + (px * 3 + c);
#pragma unroll
      for (int t = 0; t < 8; ++t) {
        int py = tly1 + iy0_1 + t - PAD;
        if ((unsigned)py < (unsigned)IMG_H)
          a = fmaf(rw1[t], colp[py * (IMG_W * 3)], a);
      }
    }
    tmp1[e] = a;
  }
  // ---- vertical pass, scale 2: 768 elements ----
  for (int e = tid; e < 768; e += 256) {
    int x = e / 3, c = e - 3 * (e / 3);
    int px = tlx2 - PAD + x;
    float a = 0.0f;
    if ((unsigned)px < (unsigned)IMG_W) {
      const float* colp = imb + (px * 3 + c);
#pragma unroll
      for (int t = 0; t < 16; ++t) {
        int py = tly2 + iy0_2 + t - PAD;
        if ((unsigned)py < (unsigned)IMG_H)
          a = fmaf(rw2[t], colp[py * (IMG_W * 3)], a);
      }
    }
    tmp2[e] = a;
  }
  __syncthreads();

  // ---- horizontal pass: raw weights from table, /wsum at end (exact) ----
  for (int o = tid; o < 384; o += 256) {
    int oo = (o >= 192) ? o - 192 : o;
    int xo = oo / 3, c = oo - 3 * xo;
    if (o < 192) {  // scale 1
      const float* wr = Ws + xo * 9;
      float sx  = ((float)xo + 0.5f) * 2.0f - 0.5f;
      int   ix0 = (int)ceilf(sx - 4.0f);
      float a = 0.0f;
#pragma unroll
      for (int t = 0; t < 8; ++t) {
        int ic = iclamp(ix0 + t, 0, 127);  // OOR taps have w==0 -> exact no-op
        a = fmaf(wr[t], tmp1[ic * 3 + c], a);
      }
      Grow[xo * 9 + 3 + c] = f2bits(a / wr[8]);
    } else {        // scale 2
      const float* wr = Ws + 576 + xo * 17;
      float sx  = ((float)xo + 0.5f) * 4.0f - 0.5f;
      int   ix0 = (int)ceilf(sx - 8.0f);
      float a = 0.0f;
#pragma unroll
      for (int t = 0; t < 16; ++t) {
        int ic = iclamp(ix0 + t, 0, 255);
        a = fmaf(wr[t], tmp2[ic * 3 + c], a);
      }
      Grow[xo * 9 + 6 + c] = f2bits(a / wr[16]);
    }
  }
}

// ---------------------------------------------------------------------------
// Split-K MFMA GEMM: partial[m][tile][n] = G[64, KTILE] @ Wt^T[KTILE, 128]
// No LDS, no barrier: every fragment element is consumed by exactly one lane,
// A-tile cross-wave reuse (4x) is served by L2. All loads are dwordx4 with
// 16 segments x 64 B per wave instruction. 18 loads/lane (was ~48 scalars).
// ---------------------------------------------------------------------------
__global__ __launch_bounds__(256) void gemm_kernel(
    const unsigned short* __restrict__ G, const unsigned short* __restrict__ Wt,
    float* __restrict__ partials) {
  const int tid  = threadIdx.x;
  const int tile = blockIdx.x;
  const int kt   = tile * KTILE;
  const int lane = tid & 63;
  const int wv   = tid >> 6;
  const int ln   = lane & 15;
  const int q    = lane >> 4;
  const int nb   = wv * 32 + ln;

  f32x4 acc[4][2];
#pragma unroll
  for (int mt = 0; mt < 4; ++mt)
#pragma unroll
    for (int nt = 0; nt < 2; ++nt) {
      acc[mt][nt][0] = 0.f; acc[mt][nt][1] = 0.f;
      acc[mt][nt][2] = 0.f; acc[mt][nt][3] = 0.f;
    }

  const unsigned short* Ab = G + kt + q * 8;
  const unsigned short* Bb = Wt + kt + q * 8;

#pragma unroll
  for (int s = 0; s < KTILE / 32; ++s) {  // 3
    short8 af[4];
#pragma unroll
    for (int mt = 0; mt < 4; ++mt)
      af[mt] = *(const short8*)(Ab + (size_t)(mt * 16 + ln) * KTOT + s * 32);
    short8 bf[2];
#pragma unroll
    for (int nt = 0; nt < 2; ++nt)
      bf[nt] = *(const short8*)(Bb + (size_t)(nb + nt * 16) * KTOT + s * 32);
#pragma unroll
    for (int mt = 0; mt < 4; ++mt)
#pragma unroll
      for (int nt = 0; nt < 2; ++nt)
        acc[mt][nt] = __builtin_amdgcn_mfma_f32_16x16x32_bf16(
            af[mt], bf[nt], acc[mt][nt], 0, 0, 0);
  }

  // C layout: col = lane&15 (+16*nt +32*wv), row = (lane>>4)*4 + i (+16*mt)
#pragma unroll
  for (int mt = 0; mt < 4; ++mt)
#pragma unroll
    for (int nt = 0; nt < 2; ++nt)
#pragma unroll
      for (int i = 0; i < 4; ++i) {
        const int row = mt * 16 + q * 4 + i;
        const int col = nb + nt * 16;
        partials[((size_t)row * NTILES + tile) * 128 + col] = acc[mt][nt][i];
      }
}

// ---------------------------------------------------------------------------
// Reduce split-K partials, add biases, fuse loc branch and output layer.
// grid: 64 blocks x 512 thr (8 waves -> 2x in-flight loads vs 4 waves).
// ---------------------------------------------------------------------------
__global__ __launch_bounds__(512) void finalize_kernel(
    const float* __restrict__ partials, const float* __restrict__ loc,
    const float* __restrict__ bg, const float* __restrict__ Wl,
    const float* __restrict__ bl, const float* __restrict__ Wo,
    const float* __restrict__ bo, float* __restrict__ out) {
  const int b   = blockIdx.x;
  const int tid = threadIdx.x;

  const float4* base = (const float4*)(partials + (size_t)b * NTILES * 128);
  float4 acc = make_float4(0.f, 0.f, 0.f, 0.f);
  // NTILES*128 = 49152 floats = 12288 float4; col = (tid&31)*4 + j
#pragma unroll 8
  for (int i = 0; i < 24; ++i) {
    float4 v = base[(size_t)i * 512 + tid];
    acc.x += v.x; acc.y += v.y; acc.z += v.z; acc.w += v.w;
  }

  __shared__ float red[16][128];
  __shared__ float h[128];
  {
    float* r = &red[tid >> 5][(tid & 31) * 4];
    r[0] = acc.x; r[1] = acc.y; r[2] = acc.z; r[3] = acc.w;
  }
  __syncthreads();
  if (tid < 128) {
    float ss = 0.0f;
#pragma unroll
    for (int g = 0; g < 16; ++g) ss += red[g][tid];
    float x1 = fmaxf(ss + bg[tid], 0.0f);
    float x2 = fmaxf(fmaf(loc[2 * b], Wl[tid],
                          fmaf(loc[2 * b + 1], Wl[128 + tid], bl[tid])),
                     0.0f);
    h[tid] = x1 + x2;
  }
  __syncthreads();
  if (tid < 256) {
    const int n = tid;
    float a = bo[n];
#pragma unroll 8
    for (int kk = 0; kk < 128; ++kk) a = fmaf(h[kk], Wo[kk * 256 + n], a);
    out[(size_t)b * 256 + n] = fmaxf(a, 0.0f);
  }
}

extern "C" void kernel_launch(void* const* d_in, const int* in_sizes, int n_in,
                              void* d_out, int out_size, void* d_ws, size_t ws_size,
                              hipStream_t stream) {
  const float* img = (const float*)d_in[0];
  const float* loc = (const float*)d_in[1];
  const float* Wg  = (const float*)d_in[2];
  const float* bg  = (const float*)d_in[3];
  const float* Wl  = (const float*)d_in[4];
  const float* bl  = (const float*)d_in[5];
  const float* Wo  = (const float*)d_in[6];
  const float* bo  = (const float*)d_in[7];
  float* out = (float*)d_out;

  char* ws = (char*)d_ws;
  unsigned short* G = (unsigned short*)ws;                           // 4,718,592 B
  float* partials   = (float*)(ws + 4718592);                        // 12,582,912 B
  unsigned short* Wt = (unsigned short*)(ws + 4718592 + 12582912);   // 9,437,184 B
  float* WTbl       = (float*)(ws + 4718592 + 12582912 + 9437184);   // 6,656 B

  prep_kernel<<<TBLK + 1, 256, 0, stream>>>(Wg, Wt, WTbl);
  glimpse_kernel<<<BATCH * 64, 256, 0, stream>>>(img, loc, WTbl, G);
  gemm_kernel<<<NTILES, 256, 0, stream>>>(G, Wt, partials);
  finalize_kernel<<<BATCH, 512, 0, stream>>>(partials, loc, bg, Wl, bl, Wo, bo, out);
}

// Round 2
// 316.431 us; speedup vs baseline: 1.0033x; 1.0033x over previous
//
#include <hip/hip_runtime.h>
#include <hip/hip_bf16.h>

#define IMG_H 512
#define IMG_W 512
#define PAD   256      // max_size = GS * 2^(N_GLIMPSES-1)
#define HP    1024     // padded height/width
#define BATCH 64
#define KTOT  36864    // 64*64*9 contraction length
#define KTILE 192      // K per GEMM block (6 MFMA k-steps of 32)
#define NKT   192      // KTOT / KTILE
#define TBLK  1152     // transpose blocks (576 k-tiles x 2 n-tiles)
#define GBLK  4096     // glimpse blocks (BATCH * 64)

typedef __attribute__((ext_vector_type(8))) short short8;
typedef __attribute__((ext_vector_type(4))) float f32x4;

// Keys cubic kernel, a = -0.5 (matches jax.image resize 'cubic')
__device__ __forceinline__ float keys_cubic(float x) {
  if (x >= 2.0f) return 0.0f;
  if (x >= 1.0f) return ((-0.5f * x + 2.5f) * x - 4.0f) * x + 2.0f;
  return ((1.5f * x - 2.5f) * x) * x + 1.0f;
}

__device__ __forceinline__ int iclamp(int v, int lo, int hi) {
  return min(max(v, lo), hi);
}
__device__ __forceinline__ unsigned short f2bits(float f) {
  __hip_bfloat16 h = __float2bfloat16(f);
  unsigned short s;
  __builtin_memcpy(&s, &h, 2);
  return s;
}

// ---------------------------------------------------------------------------
// combo_kernel: ONE dispatch for both independent preprocessing stages.
//   blocks [0, TBLK):        transpose+convert Wg[36864][128] f32 ->
//                            Wt[128][36864] bf16 (K-major GEMM B operand)
//   blocks [TBLK, TBLK+GBLK): glimpse extraction; cubic weight tables are
//                            computed per-block in LDS (cheap: 8/16 taps on
//                            threads 0..127, once per block) — removes the
//                            global WT table round-trip and the ordering
//                            dependency that forced a separate dispatch.
// LDS is a 17.4 KB union of the transpose tile and the glimpse scratch.
// ---------------------------------------------------------------------------
__global__ __launch_bounds__(256) void combo_kernel(
    const float* __restrict__ img, const float* __restrict__ loc,
    const float* __restrict__ Wg, unsigned short* __restrict__ Wt,
    unsigned short* __restrict__ G) {
  __shared__ __align__(16) float smem[4352];  // 17408 B
  const int tid = threadIdx.x;

  if (blockIdx.x < TBLK) {
    // ---- 64(k) x 64(n) tile transpose via LDS (identical to round-1) ----
    float (*T)[68] = (float(*)[68])smem;  // rows 272 B, 16B-aligned
    const int bid = blockIdx.x;
    const int kt  = (bid % 576) * 64;
    const int nt0 = (bid / 576) * 64;
    {
      const int r = tid >> 4, nc = tid & 15;
#pragma unroll
      for (int kk = 0; kk < 4; ++kk) {
        const int k = kk * 16 + r;
        const float4 v = *(const float4*)(Wg + (size_t)(kt + k) * 128 + nt0 + nc * 4);
        *(float4*)(&T[k][nc * 4]) = v;
      }
    }
    __syncthreads();
#pragma unroll
    for (int it = 0; it < 2; ++it) {
      const int item = tid + 256 * it;
      const int n = item & 63, ko = item >> 6;
      short8 o;
#pragma unroll
      for (int j = 0; j < 8; ++j) o[j] = (short)f2bits(T[ko * 8 + j][n]);
      *(short8*)(Wt + (size_t)(nt0 + n) * KTOT + kt + ko * 8) = o;
    }
    return;
  }

  // ---- glimpse block ----
  float* Ws   = smem;          // [64*9 | 64*17] raw cubic weights + row sums
  float* tmp1 = smem + 1664;   // sc=1 vertical result: 128 cols x 3 ch
  float* tmp2 = smem + 2048;   // sc=2 vertical result: 256 cols x 3 ch
  float* wv1n = smem + 2816;   // normalized vertical weights (8)
  float* wv2n = smem + 2824;   // normalized vertical weights (16)

  const int bid = blockIdx.x - TBLK;
  const int y   = bid & 63;
  const int b   = bid >> 6;

  // compute weight tables in LDS (bit-identical expressions to before)
  if (tid < 64) {
    float sx = ((float)tid + 0.5f) * 2.0f - 0.5f;
    int ix0 = (int)ceilf(sx - 4.0f);
    float ws = 0.0f;
#pragma unroll
    for (int tap = 0; tap < 8; ++tap) {
      int i = ix0 + tap;
      float w = (i >= 0 && i < 128) ? keys_cubic(fabsf(sx - (float)i) * 0.5f) : 0.0f;
      Ws[tid * 9 + tap] = w;
      ws += w;
    }
    Ws[tid * 9 + 8] = ws;
  } else if (tid < 128) {
    const int xo = tid - 64;
    float sx = ((float)xo + 0.5f) * 4.0f - 0.5f;
    int ix0 = (int)ceilf(sx - 8.0f);
    float ws = 0.0f;
#pragma unroll
    for (int tap = 0; tap < 16; ++tap) {
      int i = ix0 + tap;
      float w = (i >= 0 && i < 256) ? keys_cubic(fabsf(sx - (float)i) * 0.25f) : 0.0f;
      Ws[576 + xo * 17 + tap] = w;
      ws += w;
    }
    Ws[576 + xo * 17 + 16] = ws;
  }

  // center / top-left: bit-identical to reference fp32 math, banker's rounding
  const float cy = (loc[2 * b] + 1.0f) * 0.5f * 1024.0f;
  const float cx = (loc[2 * b + 1] + 1.0f) * 0.5f * 1024.0f;
  const int tly0 = iclamp((int)rintf(cy - 32.0f), 0, HP - 64);
  const int tlx0 = iclamp((int)rintf(cx - 32.0f), 0, HP - 64);
  const int tly1 = iclamp((int)rintf(cy - 64.0f), 0, HP - 128);
  const int tlx1 = iclamp((int)rintf(cx - 64.0f), 0, HP - 128);
  const int tly2 = iclamp((int)rintf(cy - 128.0f), 0, HP - 256);
  const int tlx2 = iclamp((int)rintf(cx - 128.0f), 0, HP - 256);
  const float* imb = img + (size_t)b * (IMG_H * IMG_W * 3);
  unsigned short* Grow = G + ((size_t)b * 64 + y) * (64 * 9);

  // ---- scale 0: 64->64 resize is exactly identity: zero-padded crop copy ----
  if (tid < 192) {
    int x = tid / 3, c = tid - 3 * (tid / 3);
    int py = tly0 + y - PAD, px = tlx0 + x - PAD;
    float v = 0.0f;
    if ((unsigned)py < (unsigned)IMG_H && (unsigned)px < (unsigned)IMG_W)
      v = imb[(py * IMG_W + px) * 3 + c];
    Grow[x * 9 + c] = f2bits(v);
  }
  __syncthreads();  // tables ready

  // normalize vertical weights once per block (w * (1/ws), exact as before)
  if (tid < 8) {
    wv1n[tid] = Ws[y * 9 + tid] * (1.0f / Ws[y * 9 + 8]);
  } else if (tid >= 64 && tid < 80) {
    const int t = tid - 64;
    wv2n[t] = Ws[576 + y * 17 + t] * (1.0f / Ws[576 + y * 17 + 16]);
  }
  __syncthreads();

  const float sy1 = ((float)y + 0.5f) * 2.0f - 0.5f;
  const int iy0_1 = (int)ceilf(sy1 - 4.0f);
  const float sy2 = ((float)y + 0.5f) * 4.0f - 0.5f;
  const int iy0_2 = (int)ceilf(sy2 - 8.0f);
  float rw1[8], rw2[16];
#pragma unroll
  for (int t = 0; t < 8; ++t) rw1[t] = wv1n[t];
#pragma unroll
  for (int t = 0; t < 16; ++t) rw2[t] = wv2n[t];

  // ---- vertical pass, scale 1: 384 elements ----
  for (int e = tid; e < 384; e += 256) {
    int x = e / 3, c = e - 3 * (e / 3);
    int px = tlx1 - PAD + x;
    float a = 0.0f;
    if ((unsigned)px < (unsigned)IMG_W) {
      const float* colp = imb + (px * 3 + c);
#pragma unroll
      for (int t = 0; t < 8; ++t) {
        int py = tly1 + iy0_1 + t - PAD;
        if ((unsigned)py < (unsigned)IMG_H)
          a = fmaf(rw1[t], colp[py * (IMG_W * 3)], a);
      }
    }
    tmp1[e] = a;
  }
  // ---- vertical pass, scale 2: 768 elements ----
  for (int e = tid; e < 768; e += 256) {
    int x = e / 3, c = e - 3 * (e / 3);
    int px = tlx2 - PAD + x;
    float a = 0.0f;
    if ((unsigned)px < (unsigned)IMG_W) {
      const float* colp = imb + (px * 3 + c);
#pragma unroll
      for (int t = 0; t < 16; ++t) {
        int py = tly2 + iy0_2 + t - PAD;
        if ((unsigned)py < (unsigned)IMG_H)
          a = fmaf(rw2[t], colp[py * (IMG_W * 3)], a);
      }
    }
    tmp2[e] = a;
  }
  __syncthreads();

  // ---- horizontal pass: raw weights from table, /wsum at end (exact) ----
  for (int o = tid; o < 384; o += 256) {
    int oo = (o >= 192) ? o - 192 : o;
    int xo = oo / 3, c = oo - 3 * xo;
    if (o < 192) {  // scale 1
      const float* wr = Ws + xo * 9;
      float sx  = ((float)xo + 0.5f) * 2.0f - 0.5f;
      int   ix0 = (int)ceilf(sx - 4.0f);
      float a = 0.0f;
#pragma unroll
      for (int t = 0; t < 8; ++t) {
        int ic = iclamp(ix0 + t, 0, 127);  // OOR taps have w==0 -> exact no-op
        a = fmaf(wr[t], tmp1[ic * 3 + c], a);
      }
      Grow[xo * 9 + 3 + c] = f2bits(a / wr[8]);
    } else {        // scale 2
      const float* wr = Ws + 576 + xo * 17;
      float sx  = ((float)xo + 0.5f) * 4.0f - 0.5f;
      int   ix0 = (int)ceilf(sx - 8.0f);
      float a = 0.0f;
#pragma unroll
      for (int t = 0; t < 16; ++t) {
        int ic = iclamp(ix0 + t, 0, 255);
        a = fmaf(wr[t], tmp2[ic * 3 + c], a);
      }
      Grow[xo * 9 + 6 + c] = f2bits(a / wr[16]);
    }
  }
}

// ---------------------------------------------------------------------------
// Split-K MFMA GEMM, KTILE=192 with 2-way N-split: 384 blocks (same occupancy
// as before), partials halved to 6.3 MB. Block bid: ktile = bid>>1 covers
// K [ktile*192, +192); nh = bid&1 covers cols [nh*64, +64); wave wv owns the
// 16-col tile at nh*64 + wv*16. No LDS, no barrier; all loads dwordx4 with
// 16 segments x 64 B per wave instruction.
// ---------------------------------------------------------------------------
__global__ __launch_bounds__(256) void gemm_kernel(
    const unsigned short* __restrict__ G, const unsigned short* __restrict__ Wt,
    float* __restrict__ partials) {
  const int tid   = threadIdx.x;
  const int bid   = blockIdx.x;
  const int ktile = bid >> 1;
  const int nh    = bid & 1;
  const int kt    = ktile * KTILE;
  const int lane  = tid & 63;
  const int wv    = tid >> 6;
  const int ln    = lane & 15;
  const int q     = lane >> 4;
  const int gcol  = nh * 64 + wv * 16 + ln;

  f32x4 acc[4];
#pragma unroll
  for (int mt = 0; mt < 4; ++mt) {
    acc[mt][0] = 0.f; acc[mt][1] = 0.f; acc[mt][2] = 0.f; acc[mt][3] = 0.f;
  }

  const unsigned short* Ab = G + kt + q * 8;
  const unsigned short* Bb = Wt + (size_t)gcol * KTOT + kt + q * 8;

#pragma unroll
  for (int s = 0; s < KTILE / 32; ++s) {  // 6
    short8 af[4];
#pragma unroll
    for (int mt = 0; mt < 4; ++mt)
      af[mt] = *(const short8*)(Ab + (size_t)(mt * 16 + ln) * KTOT + s * 32);
    const short8 bf = *(const short8*)(Bb + s * 32);
#pragma unroll
    for (int mt = 0; mt < 4; ++mt)
      acc[mt] = __builtin_amdgcn_mfma_f32_16x16x32_bf16(af[mt], bf, acc[mt], 0, 0, 0);
  }

  // C layout: col = lane&15 (+16*wv +64*nh), row = (lane>>4)*4 + i (+16*mt)
#pragma unroll
  for (int mt = 0; mt < 4; ++mt)
#pragma unroll
    for (int i = 0; i < 4; ++i) {
      const int row = mt * 16 + q * 4 + i;
      partials[((size_t)row * NKT + ktile) * 128 + gcol] = acc[mt][i];
    }
}

// ---------------------------------------------------------------------------
// Reduce split-K partials (192 tiles), add biases, fuse loc branch + output.
// grid: 64 blocks x 1024 thr (16 waves -> deep in-flight load queue; only
// 64 CUs are active so per-CU streaming depth is what matters).
// ---------------------------------------------------------------------------
__global__ __launch_bounds__(1024) void finalize_kernel(
    const float* __restrict__ partials, const float* __restrict__ loc,
    const float* __restrict__ bg, const float* __restrict__ Wl,
    const float* __restrict__ bl, const float* __restrict__ Wo,
    const float* __restrict__ bo, float* __restrict__ out) {
  const int b   = blockIdx.x;
  const int tid = threadIdx.x;

  const float4* base = (const float4*)(partials + (size_t)b * NKT * 128);
  float4 acc = make_float4(0.f, 0.f, 0.f, 0.f);
  // NKT*128 = 24576 floats = 6144 float4; col = (tid&31)*4 + j
#pragma unroll
  for (int i = 0; i < 6; ++i) {
    float4 v = base[(size_t)i * 1024 + tid];
    acc.x += v.x; acc.y += v.y; acc.z += v.z; acc.w += v.w;
  }

  __shared__ float red[32][128];
  __shared__ float h[128];
  {
    float* r = &red[tid >> 5][(tid & 31) * 4];
    r[0] = acc.x; r[1] = acc.y; r[2] = acc.z; r[3] = acc.w;
  }
  __syncthreads();
  if (tid < 128) {
    float ss = 0.0f;
#pragma unroll
    for (int g = 0; g < 32; ++g) ss += red[g][tid];
    float x1 = fmaxf(ss + bg[tid], 0.0f);
    float x2 = fmaxf(fmaf(loc[2 * b], Wl[tid],
                          fmaf(loc[2 * b + 1], Wl[128 + tid], bl[tid])),
                     0.0f);
    h[tid] = x1 + x2;
  }
  __syncthreads();
  if (tid < 256) {
    const int n = tid;
    float a = bo[n];
#pragma unroll 8
    for (int kk = 0; kk < 128; ++kk) a = fmaf(h[kk], Wo[kk * 256 + n], a);
    out[(size_t)b * 256 + n] = fmaxf(a, 0.0f);
  }
}

extern "C" void kernel_launch(void* const* d_in, const int* in_sizes, int n_in,
                              void* d_out, int out_size, void* d_ws, size_t ws_size,
                              hipStream_t stream) {
  const float* img = (const float*)d_in[0];
  const float* loc = (const float*)d_in[1];
  const float* Wg  = (const float*)d_in[2];
  const float* bg  = (const float*)d_in[3];
  const float* Wl  = (const float*)d_in[4];
  const float* bl  = (const float*)d_in[5];
  const float* Wo  = (const float*)d_in[6];
  const float* bo  = (const float*)d_in[7];
  float* out = (float*)d_out;

  char* ws = (char*)d_ws;
  unsigned short* G  = (unsigned short*)ws;                          // 4,718,592 B
  float* partials    = (float*)(ws + 4718592);                       // 6,291,456 B
  unsigned short* Wt = (unsigned short*)(ws + 4718592 + 6291456);    // 9,437,184 B

  combo_kernel<<<TBLK + GBLK, 256, 0, stream>>>(img, loc, Wg, Wt, G);
  gemm_kernel<<<NKT * 2, 256, 0, stream>>>(G, Wt, partials);
  finalize_kernel<<<BATCH, 1024, 0, stream>>>(partials, loc, bg, Wl, bl, Wo, bo, out);
}